// Round 7
// baseline (248.896 us; speedup 1.0000x reference)
//
#include <hip/hip_runtime.h>
#include <hip/hip_bf16.h>
#include <math.h>

// Shapes: B=16, H=512, L=2048, N=64
#define HH 512
#define NN 64
#define LLEN 2048
#define BB 16

typedef __attribute__((ext_vector_type(8))) short short8;
typedef __attribute__((ext_vector_type(4))) float f32x4;

__device__ inline unsigned short f2bf(float f) {
    union { float f; unsigned int u; } v; v.f = f;
    unsigned int x = v.u;
    unsigned int r = (x + 0x7fffu + ((x >> 16) & 1u)) >> 16;
    return (unsigned short)r;
}
__device__ inline float bf2f(unsigned short x) {
    union { unsigned int u; float f; } v; v.u = ((unsigned int)x) << 16;
    return v.f;
}
// packed f32x2 -> bf16x2 (RNE)
__device__ inline unsigned int pk_bf16(float a, float b) {
#if __has_builtin(__builtin_amdgcn_cvt_pk_bf16_f32)
    auto r = __builtin_amdgcn_cvt_pk_bf16_f32(a, b);
    unsigned int o; __builtin_memcpy(&o, &r, 4); return o;
#else
    return (unsigned int)f2bf(a) | ((unsigned int)f2bf(b) << 16);
#endif
}

__device__ inline float fast_rcp(float x) {
#if __has_builtin(__builtin_amdgcn_rcpf)
    return __builtin_amdgcn_rcpf(x);
#else
    return 1.0f / x;
#endif
}
__device__ inline float fast_exp2(float x) {
#if __has_builtin(__builtin_amdgcn_exp2f)
    return __builtin_amdgcn_exp2f(x);
#else
    return exp2f(x);
#endif
}
// GELU via Abramowitz-Stegun 7.1.26 erf (|erf err| <= 1.5e-7): accurate and ~14 VALU ops.
__device__ inline float gelu_erf(float x) {
    float ax = fabsf(x) * 0.7071067811865475f;   // |x|/sqrt(2)
    float t = fast_rcp(fmaf(0.3275911f, ax, 1.0f));
    float poly = t * fmaf(t, fmaf(t, fmaf(t, fmaf(t, 1.061405429f, -1.453152027f),
                                          1.421413741f), -0.284496736f), 0.254829592f);
    float e = fast_exp2(-1.4426950408889634f * ax * ax);
    float erfv = 1.0f - poly * e;                // erf(ax) in [0,1)
    erfv = copysignf(erfv, x);
    return 0.5f * x * (1.0f + erfv);
}

__device__ inline void gload_lds16(const unsigned short* g, unsigned short* l) {
    __builtin_amdgcn_global_load_lds(
        (const __attribute__((address_space(1))) void*)g,
        (__attribute__((address_space(3))) void*)l, 16, 0, 0);
}

// ---------------- K_PREP2: fused coeffs + per-h matrices + W cast.
__global__ __launch_bounds__(256) void k_prep2(
    const float* __restrict__ log_dt, const float* __restrict__ Lambda,
    const float* __restrict__ W, const float* __restrict__ D,
    const float* __restrict__ out_w,
    unsigned short* __restrict__ Tm,
    unsigned short* __restrict__ Are, unsigned short* __restrict__ Aim,
    unsigned short* __restrict__ Pre, unsigned short* __restrict__ Pim,
    float2* __restrict__ lam64,
    unsigned short* __restrict__ Wb) {
    int blk = blockIdx.x;
    int tid = threadIdx.x;
    if (blk >= 512) {   // W cast: 64 blocks x 4096 elems
        int base = (blk - 512) * 4096 + tid;
#pragma unroll
        for (int i = 0; i < 16; ++i) Wb[base + i * 256] = f2bf(out_w[base + i * 256]);
        return;
    }
    int h = blk;
    __shared__ float ar_s[64], ai_s[64], cr_s[64], ci_s[64], k_s[64];
    if (tid < 64) {
        int n = tid;
        float lre = Lambda[n * 2 + 0], lim = Lambda[n * 2 + 1];
        float dtr = expf(log_dt[h * 2 + 0]);
        float dti = expf(log_dt[h * 2 + 1]);
        float ar = dtr * lre, ai = dti * lim;
        ar_s[n] = ar; ai_s[n] = ai;
        float e64 = expf(64.f * ar);
        lam64[h * 64 + n] = make_float2(e64 * cosf(64.f * ai), e64 * sinf(64.f * ai));
        float pos = (lre > 0.0f) ? 1.0f : 0.0f;
        float pm = pos * (float)(LLEN - 1);
        float er = expf(-ar * pm);
        float epr = er * cosf(-ai * pm), epi = er * sinf(-ai * pm);
        float sgn = 1.0f - 2.0f * pos;
        float nr = ar * sgn, ni = ai * sgn;
        float en = expf(nr);
        float numr = en * cosf(ni) - 1.0f, numi = en * sinf(ni);
        float eL = expf(nr * (float)LLEN);
        float denr = eL * cosf(ni * (float)LLEN) - 1.0f;
        float deni = eL * sinf(ni * (float)LLEN);
        float xr = denr * lre - deni * lim;
        float xi = denr * lim + deni * lre;
        float d = xr * xr + xi * xi + 1e-7f;
        float rr = xr / d, ri = -xi / d;
        float wr = W[(h * 64 + n) * 2 + 0], wi = W[(h * 64 + n) * 2 + 1];
        float t1r = wr * numr - wi * numi;
        float t1i = wr * numi + wi * numr;
        float wkr = t1r * rr - t1i * ri;
        float wki = t1r * ri + t1i * rr;
        cr_s[n] = wkr * epr - wki * epi;
        ci_s[n] = wkr * epi + wki * epr;
    }
    __syncthreads();
    size_t base = (size_t)h * 4096;
#pragma unroll 4
    for (int e = 0; e < 16; ++e) {
        int idx = e * 256 + tid;       // 0..4095
        int r = idx >> 6, q = idx & 63;
        {
            float fi = (float)(63 - q);
            float w = expf(fi * ar_s[r]);
            Are[base + idx] = f2bf(w * cosf(fi * ai_s[r]));
            Aim[base + idx] = f2bf(w * sinf(fi * ai_s[r]));
        }
        {
            float t = (float)(r + 1);
            float w = expf(t * ar_s[q]);
            float pr = w * cosf(t * ai_s[q]), pii = w * sinf(t * ai_s[q]);
            Pre[base + idx] = f2bf(cr_s[q] * pr - ci_s[q] * pii);
            Pim[base + idx] = f2bf(-(cr_s[q] * pii + ci_s[q] * pr));
        }
    }
    if (tid < 64) {
        float fd = (float)tid, acc = 0.f;
        for (int n = 0; n < 64; ++n) {
            float w = expf(fd * ar_s[n]);
            acc += cr_s[n] * (w * cosf(fd * ai_s[n])) - ci_s[n] * (w * sinf(fd * ai_s[n]));
        }
        if (tid == 0) acc += D[h];
        k_s[tid] = acc;
    }
    __syncthreads();
#pragma unroll 4
    for (int e = 0; e < 16; ++e) {
        int idx = e * 256 + tid;
        int i = idx >> 6, ip = idx & 63;
        Tm[base + idx] = (ip <= i) ? f2bf(k_s[i - ip]) : (unsigned short)0;
    }
}

// ---------------- K_SCAN3: chunked MFMA scan, 4 waves/block (one (b,h) each).
// Barriers restored (round-6's wave-fence variant was nondeterministic on HW).
// Scan loop software-pipelined: V reads are recurrence-independent, issued
// 8 iterations ahead via a register ring so the serial chain is fma-only.
__global__ __launch_bounds__(256) void k_scan3(
    const float* __restrict__ u,
    const unsigned short* __restrict__ Tm,
    const unsigned short* __restrict__ Are, const unsigned short* __restrict__ Aim,
    const unsigned short* __restrict__ Pre, const unsigned short* __restrict__ Pim,
    const float2* __restrict__ lam64,
    unsigned short* __restrict__ G) {
    __shared__ unsigned short SreA[4 * 2048];
    __shared__ unsigned short SimA[4 * 2048];
    int tid = threadIdx.x;
    int wv = tid >> 6, ln = tid & 63;
    unsigned short* Sre = &SreA[wv * 2048];
    unsigned short* Sim = &SimA[wv * 2048];
    int sub = ln & 15, quad = ln >> 4;
    int bh = blockIdx.x * 4 + wv;             // h*16 + b ; 4 consecutive b share h
    int h = bh >> 4, b = bh & 15;
    const float* up = u + ((size_t)b * HH + h) * LLEN;
    unsigned short* Gp = G + ((size_t)b * HH + h) * LLEN;
    size_t mb = (size_t)h * 4096;

    // ---- u MFMA B-fragments straight from global
    short8 ufr[2][2];
#pragma unroll
    for (int kc = 0; kc < 2; ++kc)
#pragma unroll
        for (int nt = 0; nt < 2; ++nt) {
            int l = (nt * 16 + sub) * 64 + kc * 32 + quad * 8;
            float4 v0 = *(const float4*)(up + l);
            float4 v1 = *(const float4*)(up + l + 4);
            union { short8 s; uint4 u4; } q;
            q.u4 = make_uint4(pk_bf16(v0.x, v0.y), pk_bf16(v0.z, v0.w),
                              pk_bf16(v1.x, v1.y), pk_bf16(v1.z, v1.w));
            ufr[kc][nt] = q.s;
        }

    // ---- matmul1: V[n][j] = sum_i lam_n^(63-i) * U[i][j]
    f32x4 vr[4][2], vi[4][2];
#pragma unroll
    for (int mt = 0; mt < 4; ++mt)
#pragma unroll
        for (int nt = 0; nt < 2; ++nt) {
            vr[mt][nt] = (f32x4){0.f, 0.f, 0.f, 0.f};
            vi[mt][nt] = (f32x4){0.f, 0.f, 0.f, 0.f};
        }
#pragma unroll
    for (int kc = 0; kc < 2; ++kc) {
#pragma unroll
        for (int mt = 0; mt < 4; ++mt) {
            size_t ab = mb + (size_t)(mt * 16 + sub) * 64 + kc * 32 + quad * 8;
            short8 ar8 = *(const short8*)(Are + ab);
            short8 ai8 = *(const short8*)(Aim + ab);
            vr[mt][0] = __builtin_amdgcn_mfma_f32_16x16x32_bf16(ar8, ufr[kc][0], vr[mt][0], 0, 0, 0);
            vr[mt][1] = __builtin_amdgcn_mfma_f32_16x16x32_bf16(ar8, ufr[kc][1], vr[mt][1], 0, 0, 0);
            vi[mt][0] = __builtin_amdgcn_mfma_f32_16x16x32_bf16(ai8, ufr[kc][0], vi[mt][0], 0, 0, 0);
            vi[mt][1] = __builtin_amdgcn_mfma_f32_16x16x32_bf16(ai8, ufr[kc][1], vi[mt][1], 0, 0, 0);
        }
    }
    // write V -> LDS [row j][elem n], additive swizzle
#pragma unroll
    for (int mt = 0; mt < 4; ++mt)
#pragma unroll
        for (int nt = 0; nt < 2; ++nt) {
            int jj = nt * 16 + sub;
            int c = 2 * mt + (quad >> 1);
            int ofs = jj * 64 + ((c + jj) & 7) * 8 + (quad & 1) * 4;
            uint2 pr, pi;
            pr.x = pk_bf16(vr[mt][nt][0], vr[mt][nt][1]);
            pr.y = pk_bf16(vr[mt][nt][2], vr[mt][nt][3]);
            pi.x = pk_bf16(vi[mt][nt][0], vi[mt][nt][1]);
            pi.y = pk_bf16(vi[mt][nt][2], vi[mt][nt][3]);
            *(uint2*)&Sre[ofs] = pr;
            *(uint2*)&Sim[ofs] = pi;
        }
    __syncthreads();

    // ---- scan over 32 chunks: lane = mode n. S[j] = state before chunk j.
    // Software-pipelined: V reads issued PD iterations ahead (independent of
    // the recurrence); state writes go to rows already consumed.
    {
        float2 l64 = lam64[(size_t)h * 64 + ln];
        float sr = 0.f, si = 0.f;
        int pb = ln >> 3, eo = ln & 7;
        const int PD = 8;
        float pvr[PD], pvi[PD];
#pragma unroll
        for (int t = 0; t < PD; ++t) {
            int a = t * 64 + ((pb + t) & 7) * 8 + eo;
            pvr[t] = bf2f(Sre[a]);
            pvi[t] = bf2f(Sim[a]);
        }
#pragma unroll
        for (int j = 0; j < 32; ++j) {
            int slot = j & (PD - 1);
            float vrr = pvr[slot], vii = pvi[slot];
            int a = j * 64 + ((pb + j) & 7) * 8 + eo;
            unsigned int p = pk_bf16(sr, si);
            Sre[a] = (unsigned short)(p & 0xffffu);
            Sim[a] = (unsigned short)(p >> 16);
            if (j + PD < 32) {
                int a2 = (j + PD) * 64 + ((pb + j + PD) & 7) * 8 + eo;
                pvr[slot] = bf2f(Sre[a2]);
                pvi[slot] = bf2f(Sim[a2]);
            }
            float nr = fmaf(l64.x, sr, fmaf(-l64.y, si, vrr));
            float ni = fmaf(l64.y, sr, fmaf(l64.x, si, vii));
            sr = nr; si = ni;
        }
    }
    __syncthreads();

    // ---- matmul2+3: Y[i][j] = T@U + Pre@Sre + (-Pim)@Sim
    f32x4 y[4][2];
#pragma unroll
    for (int mt = 0; mt < 4; ++mt)
#pragma unroll
        for (int nt = 0; nt < 2; ++nt) y[mt][nt] = (f32x4){0.f, 0.f, 0.f, 0.f};
#pragma unroll
    for (int kc = 0; kc < 2; ++kc) {
        int c = kc * 4 + quad;
        int r0 = sub, r1 = 16 + sub;
        short8 bsr0 = *(const short8*)&Sre[r0 * 64 + ((c + r0) & 7) * 8];
        short8 bsr1 = *(const short8*)&Sre[r1 * 64 + ((c + r1) & 7) * 8];
        short8 bsi0 = *(const short8*)&Sim[r0 * 64 + ((c + r0) & 7) * 8];
        short8 bsi1 = *(const short8*)&Sim[r1 * 64 + ((c + r1) & 7) * 8];
#pragma unroll
        for (int mt = 0; mt < 4; ++mt) {
            size_t ab = mb + (size_t)(mt * 16 + sub) * 64 + kc * 32 + quad * 8;
            short8 at8 = *(const short8*)(Tm + ab);
            short8 pr8 = *(const short8*)(Pre + ab);
            short8 pi8 = *(const short8*)(Pim + ab);
            y[mt][0] = __builtin_amdgcn_mfma_f32_16x16x32_bf16(at8, ufr[kc][0], y[mt][0], 0, 0, 0);
            y[mt][1] = __builtin_amdgcn_mfma_f32_16x16x32_bf16(at8, ufr[kc][1], y[mt][1], 0, 0, 0);
            y[mt][0] = __builtin_amdgcn_mfma_f32_16x16x32_bf16(pr8, bsr0, y[mt][0], 0, 0, 0);
            y[mt][1] = __builtin_amdgcn_mfma_f32_16x16x32_bf16(pr8, bsr1, y[mt][1], 0, 0, 0);
            y[mt][0] = __builtin_amdgcn_mfma_f32_16x16x32_bf16(pi8, bsi0, y[mt][0], 0, 0, 0);
            y[mt][1] = __builtin_amdgcn_mfma_f32_16x16x32_bf16(pi8, bsi1, y[mt][1], 0, 0, 0);
        }
    }

    // ---- accurate GELU + direct store (uint2; 4 mt-stores complete each 128B line in L2)
#pragma unroll
    for (int mt = 0; mt < 4; ++mt)
#pragma unroll
        for (int nt = 0; nt < 2; ++nt) {
            int l = (nt * 16 + sub) * 64 + mt * 16 + quad * 4;
            float g0 = gelu_erf(y[mt][nt][0]);
            float g1 = gelu_erf(y[mt][nt][1]);
            float g2 = gelu_erf(y[mt][nt][2]);
            float g3 = gelu_erf(y[mt][nt][3]);
            uint2 pv;
            pv.x = pk_bf16(g0, g1);
            pv.y = pk_bf16(g2, g3);
            *(uint2*)(Gp + l) = pv;
        }
}

// ---------------- K_TR: G[b][u][l] -> Gt[b][l][u], 64x64 LDS tiles
__global__ __launch_bounds__(256) void k_tr(const unsigned short* __restrict__ G,
                                            unsigned short* __restrict__ Gt) {
    __shared__ unsigned short T[64 * 72];
    int tid = threadIdx.x;
    int l0 = blockIdx.x * 64, u0 = blockIdx.y * 64, b = blockIdx.z;
    {
        int ur = tid >> 2, ls = (tid & 3) * 16;
        const unsigned short* src = G + ((size_t)(b * HH + u0 + ur)) * LLEN + l0 + ls;
        *(uint4*)&T[ur * 72 + ls]     = *(const uint4*)(src);
        *(uint4*)&T[ur * 72 + ls + 8] = *(const uint4*)(src + 8);
    }
    __syncthreads();
    {
        int lr = tid >> 2, us = (tid & 3) * 16;
        unsigned short tmp[16];
#pragma unroll
        for (int k2 = 0; k2 < 16; ++k2) tmp[k2] = T[(us + k2) * 72 + lr];
        unsigned short* dst = Gt + ((size_t)(b * LLEN + l0 + lr)) * HH + u0 + us;
        *(uint4*)(dst)     = *(uint4*)&tmp[0];
        *(uint4*)(dst + 8) = *(uint4*)&tmp[8];
    }
}

// ---------------- K_PROJ: out[b,v,l] = sum_u W[v,u]*Gt[b,l,u] + bias[v]
__global__ __launch_bounds__(256) void k_proj(
    const unsigned short* __restrict__ Gt,   // (B,L,H) bf16
    const unsigned short* __restrict__ Wb,   // (H,H) bf16
    const float* __restrict__ bias,          // (H,1)
    float* __restrict__ out) {               // (B,H,L)
    __shared__ unsigned short As[128 * 64];
    __shared__ unsigned short Bs[128 * 64];
    int tid = threadIdx.x;
    int w = tid >> 6, ln = tid & 63;
    int wm = w & 1, wn = w >> 1;
    int quad = ln >> 4, sub = ln & 15;
    int v0 = blockIdx.x * 128, l0 = blockIdx.y * 128, b = blockIdx.z;
    int r_in = ln >> 3, cch = ln & 7;
    int gch = cch ^ r_in;

    f32x4 acc[4][4];
#pragma unroll
    for (int mt = 0; mt < 4; ++mt)
#pragma unroll
        for (int nt = 0; nt < 4; ++nt) acc[mt][nt] = (f32x4){0.f, 0.f, 0.f, 0.f};

    for (int k0 = 0; k0 < HH; k0 += 64) {
        __syncthreads();
#pragma unroll
        for (int i = 0; i < 4; ++i) {
            int row = w * 32 + i * 8 + r_in;
            const unsigned short* ga = Wb + (size_t)(v0 + row) * HH + k0 + gch * 8;
            gload_lds16(ga, &As[(w * 32 + i * 8) * 64]);
            const unsigned short* gb = Gt + ((size_t)(b * LLEN + l0 + row)) * HH + k0 + gch * 8;
            gload_lds16(gb, &Bs[(w * 32 + i * 8) * 64]);
        }
        __syncthreads();
#pragma unroll
        for (int kc = 0; kc < 2; ++kc) {
            int ch = (kc * 4 + quad) ^ (sub & 7);
            short8 af[4], bf[4];
#pragma unroll
            for (int mt = 0; mt < 4; ++mt)
                af[mt] = *(const short8*)&As[(wm * 64 + mt * 16 + sub) * 64 + ch * 8];
#pragma unroll
            for (int nt = 0; nt < 4; ++nt)
                bf[nt] = *(const short8*)&Bs[(wn * 64 + nt * 16 + sub) * 64 + ch * 8];
#pragma unroll
            for (int mt = 0; mt < 4; ++mt)
#pragma unroll
                for (int nt = 0; nt < 4; ++nt)
                    acc[mt][nt] = __builtin_amdgcn_mfma_f32_16x16x32_bf16(af[mt], bf[nt], acc[mt][nt], 0, 0, 0);
        }
    }
#pragma unroll
    for (int mt = 0; mt < 4; ++mt) {
#pragma unroll
        for (int i = 0; i < 4; ++i) {
            int v = v0 + wm * 64 + mt * 16 + quad * 4 + i;
            float bv = bias[v];
#pragma unroll
            for (int nt = 0; nt < 4; ++nt) {
                int l = l0 + wn * 64 + nt * 16 + sub;
                out[((size_t)b * HH + v) * LLEN + l] = acc[mt][nt][i] + bv;
            }
        }
    }
}

extern "C" void kernel_launch(void* const* d_in, const int* in_sizes, int n_in,
                              void* d_out, int out_size, void* d_ws, size_t ws_size,
                              hipStream_t stream) {
    const float* u       = (const float*)d_in[0];
    const float* log_dt  = (const float*)d_in[1];
    const float* Lambda  = (const float*)d_in[2];
    const float* W       = (const float*)d_in[3];
    const float* D       = (const float*)d_in[4];
    const float* out_w   = (const float*)d_in[5];
    const float* out_b   = (const float*)d_in[6];
    float* out = (float*)d_out;

    char* ws = (char*)d_ws;
    unsigned short* Wb = (unsigned short*)(ws + 524288);   // 512KB..1MB
    unsigned short* G  = (unsigned short*)(ws + 1048576);  // 32 MiB -> ends 34,603,008
    size_t moff = 34603008;
    const size_t MSZ = (size_t)HH * 4096 * 2;              // 4 MiB per matrix
    unsigned short* TmB  = (unsigned short*)(ws + moff);
    unsigned short* AreB = (unsigned short*)(ws + moff + 1 * MSZ);
    unsigned short* AimB = (unsigned short*)(ws + moff + 2 * MSZ);
    unsigned short* PreB = (unsigned short*)(ws + moff + 3 * MSZ);
    unsigned short* PimB = (unsigned short*)(ws + moff + 4 * MSZ);
    float2* lam64B = (float2*)(ws + moff + 5 * MSZ);
    // Gt overlaps the (dead after k_scan3) matrix region
    unsigned short* Gt = (unsigned short*)(ws + moff);

    hipLaunchKernelGGL(k_prep2, dim3(576), dim3(256), 0, stream,
                       log_dt, Lambda, W, D, out_w,
                       TmB, AreB, AimB, PreB, PimB, lam64B, Wb);
    hipLaunchKernelGGL(k_scan3, dim3(2048), dim3(256), 0, stream,
                       u, TmB, AreB, AimB, PreB, PimB, lam64B, G);
    hipLaunchKernelGGL(k_tr, dim3(32, 8, 16), dim3(256), 0, stream, G, Gt);
    hipLaunchKernelGGL(k_proj, dim3(4, 16, 16), dim3(256), 0, stream,
                       Gt, Wb, out_b, out);
}

// Round 8
// 230.339 us; speedup vs baseline: 1.0806x; 1.0806x over previous
//
#include <hip/hip_runtime.h>
#include <hip/hip_bf16.h>
#include <math.h>

// Shapes: B=16, H=512, L=2048, N=64
#define HH 512
#define NN 64
#define LLEN 2048
#define BB 16

typedef __attribute__((ext_vector_type(8))) short short8;
typedef __attribute__((ext_vector_type(4))) float f32x4;

__device__ inline unsigned short f2bf(float f) {
    union { float f; unsigned int u; } v; v.f = f;
    unsigned int x = v.u;
    unsigned int r = (x + 0x7fffu + ((x >> 16) & 1u)) >> 16;
    return (unsigned short)r;
}
__device__ inline float bf2f(unsigned short x) {
    union { unsigned int u; float f; } v; v.u = ((unsigned int)x) << 16;
    return v.f;
}
// packed f32x2 -> bf16x2 (RNE)
__device__ inline unsigned int pk_bf16(float a, float b) {
#if __has_builtin(__builtin_amdgcn_cvt_pk_bf16_f32)
    auto r = __builtin_amdgcn_cvt_pk_bf16_f32(a, b);
    unsigned int o; __builtin_memcpy(&o, &r, 4); return o;
#else
    return (unsigned int)f2bf(a) | ((unsigned int)f2bf(b) << 16);
#endif
}

__device__ inline float fast_rcp(float x) {
#if __has_builtin(__builtin_amdgcn_rcpf)
    return __builtin_amdgcn_rcpf(x);
#else
    return 1.0f / x;
#endif
}
__device__ inline float fast_exp2(float x) {
#if __has_builtin(__builtin_amdgcn_exp2f)
    return __builtin_amdgcn_exp2f(x);
#else
    return exp2f(x);
#endif
}
// GELU via Abramowitz-Stegun 7.1.26 erf (|erf err| <= 1.5e-7): accurate, ~14 VALU ops.
__device__ inline float gelu_erf(float x) {
    float ax = fabsf(x) * 0.7071067811865475f;   // |x|/sqrt(2)
    float t = fast_rcp(fmaf(0.3275911f, ax, 1.0f));
    float poly = t * fmaf(t, fmaf(t, fmaf(t, fmaf(t, 1.061405429f, -1.453152027f),
                                          1.421413741f), -0.284496736f), 0.254829592f);
    float e = fast_exp2(-1.4426950408889634f * ax * ax);
    float erfv = 1.0f - poly * e;                // erf(ax) in [0,1)
    erfv = copysignf(erfv, x);
    return 0.5f * x * (1.0f + erfv);
}

__device__ inline void gload_lds16(const unsigned short* g, unsigned short* l) {
    __builtin_amdgcn_global_load_lds(
        (const __attribute__((address_space(1))) void*)g,
        (__attribute__((address_space(3))) void*)l, 16, 0, 0);
}

// ---------------- K_PREP2: fused coeffs + per-h matrices + W cast.
// Bulk loops use HW transcendentals (__expf/__sinf/__cosf: v_exp/v_sin/v_cos,
// 1-2 instr vs ~20 for libm) — outputs are bf16-rounded so 2-ulp is plenty.
// lam64 (fp32, error compounds x32 in the scan) keeps precise libm.
__global__ __launch_bounds__(256) void k_prep2(
    const float* __restrict__ log_dt, const float* __restrict__ Lambda,
    const float* __restrict__ W, const float* __restrict__ D,
    const float* __restrict__ out_w,
    unsigned short* __restrict__ Tm,
    unsigned short* __restrict__ Are, unsigned short* __restrict__ Aim,
    unsigned short* __restrict__ Pre, unsigned short* __restrict__ Pim,
    float2* __restrict__ lam64,
    unsigned short* __restrict__ Wb) {
    int blk = blockIdx.x;
    int tid = threadIdx.x;
    if (blk >= 512) {   // W cast: 64 blocks x 4096 elems
        int base = (blk - 512) * 4096 + tid;
#pragma unroll
        for (int i = 0; i < 16; ++i) Wb[base + i * 256] = f2bf(out_w[base + i * 256]);
        return;
    }
    int h = blk;
    __shared__ float ar_s[64], ai_s[64], cr_s[64], ci_s[64], k_s[64];
    if (tid < 64) {
        int n = tid;
        float lre = Lambda[n * 2 + 0], lim = Lambda[n * 2 + 1];
        float dtr = expf(log_dt[h * 2 + 0]);
        float dti = expf(log_dt[h * 2 + 1]);
        float ar = dtr * lre, ai = dti * lim;
        ar_s[n] = ar; ai_s[n] = ai;
        float e64 = expf(64.f * ar);
        lam64[h * 64 + n] = make_float2(e64 * cosf(64.f * ai), e64 * sinf(64.f * ai));
        float pos = (lre > 0.0f) ? 1.0f : 0.0f;
        float pm = pos * (float)(LLEN - 1);
        float er = expf(-ar * pm);
        float epr = er * cosf(-ai * pm), epi = er * sinf(-ai * pm);
        float sgn = 1.0f - 2.0f * pos;
        float nr = ar * sgn, ni = ai * sgn;
        float en = expf(nr);
        float numr = en * cosf(ni) - 1.0f, numi = en * sinf(ni);
        float eL = expf(nr * (float)LLEN);
        float denr = eL * cosf(ni * (float)LLEN) - 1.0f;
        float deni = eL * sinf(ni * (float)LLEN);
        float xr = denr * lre - deni * lim;
        float xi = denr * lim + deni * lre;
        float d = xr * xr + xi * xi + 1e-7f;
        float rr = xr / d, ri = -xi / d;
        float wr = W[(h * 64 + n) * 2 + 0], wi = W[(h * 64 + n) * 2 + 1];
        float t1r = wr * numr - wi * numi;
        float t1i = wr * numi + wi * numr;
        float wkr = t1r * rr - t1i * ri;
        float wki = t1r * ri + t1i * rr;
        cr_s[n] = wkr * epr - wki * epi;
        ci_s[n] = wkr * epi + wki * epr;
    }
    __syncthreads();
    size_t base = (size_t)h * 4096;
#pragma unroll 4
    for (int e = 0; e < 16; ++e) {
        int idx = e * 256 + tid;       // 0..4095
        int r = idx >> 6, q = idx & 63;
        {
            float fi = (float)(63 - q);
            float w = __expf(fi * ar_s[r]);
            Are[base + idx] = f2bf(w * __cosf(fi * ai_s[r]));
            Aim[base + idx] = f2bf(w * __sinf(fi * ai_s[r]));
        }
        {
            float t = (float)(r + 1);
            float w = __expf(t * ar_s[q]);
            float pr = w * __cosf(t * ai_s[q]), pii = w * __sinf(t * ai_s[q]);
            Pre[base + idx] = f2bf(cr_s[q] * pr - ci_s[q] * pii);
            Pim[base + idx] = f2bf(-(cr_s[q] * pii + ci_s[q] * pr));
        }
    }
    if (tid < 64) {
        float fd = (float)tid, acc = 0.f;
        for (int n = 0; n < 64; ++n) {
            float w = __expf(fd * ar_s[n]);
            acc += cr_s[n] * (w * __cosf(fd * ai_s[n])) - ci_s[n] * (w * __sinf(fd * ai_s[n]));
        }
        if (tid == 0) acc += D[h];
        k_s[tid] = acc;
    }
    __syncthreads();
#pragma unroll 4
    for (int e = 0; e < 16; ++e) {
        int idx = e * 256 + tid;
        int i = idx >> 6, ip = idx & 63;
        Tm[base + idx] = (ip <= i) ? f2bf(k_s[i - ip]) : (unsigned short)0;
    }
}

// ---------------- K_SCAN3: chunked MFMA scan, 4 waves/block (one (b,h) each).
// r5-form scan loop (simple serial RMW — r7's register-ring pipeline regressed).
__global__ __launch_bounds__(256) void k_scan3(
    const float* __restrict__ u,
    const unsigned short* __restrict__ Tm,
    const unsigned short* __restrict__ Are, const unsigned short* __restrict__ Aim,
    const unsigned short* __restrict__ Pre, const unsigned short* __restrict__ Pim,
    const float2* __restrict__ lam64,
    unsigned short* __restrict__ G) {
    __shared__ unsigned short SreA[4 * 2048];
    __shared__ unsigned short SimA[4 * 2048];
    int tid = threadIdx.x;
    int wv = tid >> 6, ln = tid & 63;
    unsigned short* Sre = &SreA[wv * 2048];
    unsigned short* Sim = &SimA[wv * 2048];
    int sub = ln & 15, quad = ln >> 4;
    int bh = blockIdx.x * 4 + wv;             // h*16 + b ; 4 consecutive b share h
    int h = bh >> 4, b = bh & 15;
    const float* up = u + ((size_t)b * HH + h) * LLEN;
    unsigned short* Gp = G + ((size_t)b * HH + h) * LLEN;
    size_t mb = (size_t)h * 4096;

    // ---- u MFMA B-fragments straight from global
    short8 ufr[2][2];
#pragma unroll
    for (int kc = 0; kc < 2; ++kc)
#pragma unroll
        for (int nt = 0; nt < 2; ++nt) {
            int l = (nt * 16 + sub) * 64 + kc * 32 + quad * 8;
            float4 v0 = *(const float4*)(up + l);
            float4 v1 = *(const float4*)(up + l + 4);
            union { short8 s; uint4 u4; } q;
            q.u4 = make_uint4(pk_bf16(v0.x, v0.y), pk_bf16(v0.z, v0.w),
                              pk_bf16(v1.x, v1.y), pk_bf16(v1.z, v1.w));
            ufr[kc][nt] = q.s;
        }

    // ---- matmul1: V[n][j] = sum_i lam_n^(63-i) * U[i][j]
    f32x4 vr[4][2], vi[4][2];
#pragma unroll
    for (int mt = 0; mt < 4; ++mt)
#pragma unroll
        for (int nt = 0; nt < 2; ++nt) {
            vr[mt][nt] = (f32x4){0.f, 0.f, 0.f, 0.f};
            vi[mt][nt] = (f32x4){0.f, 0.f, 0.f, 0.f};
        }
#pragma unroll
    for (int kc = 0; kc < 2; ++kc) {
#pragma unroll
        for (int mt = 0; mt < 4; ++mt) {
            size_t ab = mb + (size_t)(mt * 16 + sub) * 64 + kc * 32 + quad * 8;
            short8 ar8 = *(const short8*)(Are + ab);
            short8 ai8 = *(const short8*)(Aim + ab);
            vr[mt][0] = __builtin_amdgcn_mfma_f32_16x16x32_bf16(ar8, ufr[kc][0], vr[mt][0], 0, 0, 0);
            vr[mt][1] = __builtin_amdgcn_mfma_f32_16x16x32_bf16(ar8, ufr[kc][1], vr[mt][1], 0, 0, 0);
            vi[mt][0] = __builtin_amdgcn_mfma_f32_16x16x32_bf16(ai8, ufr[kc][0], vi[mt][0], 0, 0, 0);
            vi[mt][1] = __builtin_amdgcn_mfma_f32_16x16x32_bf16(ai8, ufr[kc][1], vi[mt][1], 0, 0, 0);
        }
    }
    // write V -> LDS [row j][elem n], additive swizzle
#pragma unroll
    for (int mt = 0; mt < 4; ++mt)
#pragma unroll
        for (int nt = 0; nt < 2; ++nt) {
            int jj = nt * 16 + sub;
            int c = 2 * mt + (quad >> 1);
            int ofs = jj * 64 + ((c + jj) & 7) * 8 + (quad & 1) * 4;
            uint2 pr, pi;
            pr.x = pk_bf16(vr[mt][nt][0], vr[mt][nt][1]);
            pr.y = pk_bf16(vr[mt][nt][2], vr[mt][nt][3]);
            pi.x = pk_bf16(vi[mt][nt][0], vi[mt][nt][1]);
            pi.y = pk_bf16(vi[mt][nt][2], vi[mt][nt][3]);
            *(uint2*)&Sre[ofs] = pr;
            *(uint2*)&Sim[ofs] = pi;
        }
    __syncthreads();

    // ---- scan over 32 chunks: lane = mode n. S[j] = state before chunk j (in-place).
    {
        float2 l64 = lam64[(size_t)h * 64 + ln];
        float sr = 0.f, si = 0.f;
        int pb = ln >> 3, eo = ln & 7;
        for (int j = 0; j < 32; ++j) {
            int a = j * 64 + ((pb + j) & 7) * 8 + eo;
            float vrr = bf2f(Sre[a]);
            float vii = bf2f(Sim[a]);
            unsigned int p = pk_bf16(sr, si);
            Sre[a] = (unsigned short)(p & 0xffffu);
            Sim[a] = (unsigned short)(p >> 16);
            float nr = fmaf(l64.x, sr, fmaf(-l64.y, si, vrr));
            float ni = fmaf(l64.y, sr, fmaf(l64.x, si, vii));
            sr = nr; si = ni;
        }
    }
    __syncthreads();

    // ---- matmul2+3: Y[i][j] = T@U + Pre@Sre + (-Pim)@Sim
    f32x4 y[4][2];
#pragma unroll
    for (int mt = 0; mt < 4; ++mt)
#pragma unroll
        for (int nt = 0; nt < 2; ++nt) y[mt][nt] = (f32x4){0.f, 0.f, 0.f, 0.f};
#pragma unroll
    for (int kc = 0; kc < 2; ++kc) {
        int c = kc * 4 + quad;
        int r0 = sub, r1 = 16 + sub;
        short8 bsr0 = *(const short8*)&Sre[r0 * 64 + ((c + r0) & 7) * 8];
        short8 bsr1 = *(const short8*)&Sre[r1 * 64 + ((c + r1) & 7) * 8];
        short8 bsi0 = *(const short8*)&Sim[r0 * 64 + ((c + r0) & 7) * 8];
        short8 bsi1 = *(const short8*)&Sim[r1 * 64 + ((c + r1) & 7) * 8];
#pragma unroll
        for (int mt = 0; mt < 4; ++mt) {
            size_t ab = mb + (size_t)(mt * 16 + sub) * 64 + kc * 32 + quad * 8;
            short8 at8 = *(const short8*)(Tm + ab);
            short8 pr8 = *(const short8*)(Pre + ab);
            short8 pi8 = *(const short8*)(Pim + ab);
            y[mt][0] = __builtin_amdgcn_mfma_f32_16x16x32_bf16(at8, ufr[kc][0], y[mt][0], 0, 0, 0);
            y[mt][1] = __builtin_amdgcn_mfma_f32_16x16x32_bf16(at8, ufr[kc][1], y[mt][1], 0, 0, 0);
            y[mt][0] = __builtin_amdgcn_mfma_f32_16x16x32_bf16(pr8, bsr0, y[mt][0], 0, 0, 0);
            y[mt][1] = __builtin_amdgcn_mfma_f32_16x16x32_bf16(pr8, bsr1, y[mt][1], 0, 0, 0);
            y[mt][0] = __builtin_amdgcn_mfma_f32_16x16x32_bf16(pi8, bsi0, y[mt][0], 0, 0, 0);
            y[mt][1] = __builtin_amdgcn_mfma_f32_16x16x32_bf16(pi8, bsi1, y[mt][1], 0, 0, 0);
        }
    }

    // ---- accurate GELU + direct store (uint2; 4 mt-stores complete each 128B line in L2)
#pragma unroll
    for (int mt = 0; mt < 4; ++mt)
#pragma unroll
        for (int nt = 0; nt < 2; ++nt) {
            int l = (nt * 16 + sub) * 64 + mt * 16 + quad * 4;
            float g0 = gelu_erf(y[mt][nt][0]);
            float g1 = gelu_erf(y[mt][nt][1]);
            float g2 = gelu_erf(y[mt][nt][2]);
            float g3 = gelu_erf(y[mt][nt][3]);
            uint2 pv;
            pv.x = pk_bf16(g0, g1);
            pv.y = pk_bf16(g2, g3);
            *(uint2*)(Gp + l) = pv;
        }
}

// ---------------- K_TR: G[b][u][l] -> Gt[b][l][u], 64x64 LDS tiles
__global__ __launch_bounds__(256) void k_tr(const unsigned short* __restrict__ G,
                                            unsigned short* __restrict__ Gt) {
    __shared__ unsigned short T[64 * 72];
    int tid = threadIdx.x;
    int l0 = blockIdx.x * 64, u0 = blockIdx.y * 64, b = blockIdx.z;
    {
        int ur = tid >> 2, ls = (tid & 3) * 16;
        const unsigned short* src = G + ((size_t)(b * HH + u0 + ur)) * LLEN + l0 + ls;
        *(uint4*)&T[ur * 72 + ls]     = *(const uint4*)(src);
        *(uint4*)&T[ur * 72 + ls + 8] = *(const uint4*)(src + 8);
    }
    __syncthreads();
    {
        int lr = tid >> 2, us = (tid & 3) * 16;
        unsigned short tmp[16];
#pragma unroll
        for (int k2 = 0; k2 < 16; ++k2) tmp[k2] = T[(us + k2) * 72 + lr];
        unsigned short* dst = Gt + ((size_t)(b * LLEN + l0 + lr)) * HH + u0 + us;
        *(uint4*)(dst)     = *(uint4*)&tmp[0];
        *(uint4*)(dst + 8) = *(uint4*)&tmp[8];
    }
}

// ---------------- K_PROJ: out[b,v,l] = sum_u W[v,u]*Gt[b,l,u] + bias[v]
__global__ __launch_bounds__(256) void k_proj(
    const unsigned short* __restrict__ Gt,   // (B,L,H) bf16
    const unsigned short* __restrict__ Wb,   // (H,H) bf16
    const float* __restrict__ bias,          // (H,1)
    float* __restrict__ out) {               // (B,H,L)
    __shared__ unsigned short As[128 * 64];
    __shared__ unsigned short Bs[128 * 64];
    int tid = threadIdx.x;
    int w = tid >> 6, ln = tid & 63;
    int wm = w & 1, wn = w >> 1;
    int quad = ln >> 4, sub = ln & 15;
    int v0 = blockIdx.x * 128, l0 = blockIdx.y * 128, b = blockIdx.z;
    int r_in = ln >> 3, cch = ln & 7;
    int gch = cch ^ r_in;

    f32x4 acc[4][4];
#pragma unroll
    for (int mt = 0; mt < 4; ++mt)
#pragma unroll
        for (int nt = 0; nt < 4; ++nt) acc[mt][nt] = (f32x4){0.f, 0.f, 0.f, 0.f};

    for (int k0 = 0; k0 < HH; k0 += 64) {
        __syncthreads();
#pragma unroll
        for (int i = 0; i < 4; ++i) {
            int row = w * 32 + i * 8 + r_in;
            const unsigned short* ga = Wb + (size_t)(v0 + row) * HH + k0 + gch * 8;
            gload_lds16(ga, &As[(w * 32 + i * 8) * 64]);
            const unsigned short* gb = Gt + ((size_t)(b * LLEN + l0 + row)) * HH + k0 + gch * 8;
            gload_lds16(gb, &Bs[(w * 32 + i * 8) * 64]);
        }
        __syncthreads();
#pragma unroll
        for (int kc = 0; kc < 2; ++kc) {
            int ch = (kc * 4 + quad) ^ (sub & 7);
            short8 af[4], bf[4];
#pragma unroll
            for (int mt = 0; mt < 4; ++mt)
                af[mt] = *(const short8*)&As[(wm * 64 + mt * 16 + sub) * 64 + ch * 8];
#pragma unroll
            for (int nt = 0; nt < 4; ++nt)
                bf[nt] = *(const short8*)&Bs[(wn * 64 + nt * 16 + sub) * 64 + ch * 8];
#pragma unroll
            for (int mt = 0; mt < 4; ++mt)
#pragma unroll
                for (int nt = 0; nt < 4; ++nt)
                    acc[mt][nt] = __builtin_amdgcn_mfma_f32_16x16x32_bf16(af[mt], bf[nt], acc[mt][nt], 0, 0, 0);
        }
    }
#pragma unroll
    for (int mt = 0; mt < 4; ++mt) {
#pragma unroll
        for (int i = 0; i < 4; ++i) {
            int v = v0 + wm * 64 + mt * 16 + quad * 4 + i;
            float bv = bias[v];
#pragma unroll
            for (int nt = 0; nt < 4; ++nt) {
                int l = l0 + wn * 64 + nt * 16 + sub;
                out[((size_t)b * HH + v) * LLEN + l] = acc[mt][nt][i] + bv;
            }
        }
    }
}

extern "C" void kernel_launch(void* const* d_in, const int* in_sizes, int n_in,
                              void* d_out, int out_size, void* d_ws, size_t ws_size,
                              hipStream_t stream) {
    const float* u       = (const float*)d_in[0];
    const float* log_dt  = (const float*)d_in[1];
    const float* Lambda  = (const float*)d_in[2];
    const float* W       = (const float*)d_in[3];
    const float* D       = (const float*)d_in[4];
    const float* out_w   = (const float*)d_in[5];
    const float* out_b   = (const float*)d_in[6];
    float* out = (float*)d_out;

    char* ws = (char*)d_ws;
    unsigned short* Wb = (unsigned short*)(ws + 524288);   // 512KB..1MB
    unsigned short* G  = (unsigned short*)(ws + 1048576);  // 32 MiB -> ends 34,603,008
    size_t moff = 34603008;
    const size_t MSZ = (size_t)HH * 4096 * 2;              // 4 MiB per matrix
    unsigned short* TmB  = (unsigned short*)(ws + moff);
    unsigned short* AreB = (unsigned short*)(ws + moff + 1 * MSZ);
    unsigned short* AimB = (unsigned short*)(ws + moff + 2 * MSZ);
    unsigned short* PreB = (unsigned short*)(ws + moff + 3 * MSZ);
    unsigned short* PimB = (unsigned short*)(ws + moff + 4 * MSZ);
    float2* lam64B = (float2*)(ws + moff + 5 * MSZ);
    // Gt overlaps the (dead after k_scan3) matrix region
    unsigned short* Gt = (unsigned short*)(ws + moff);

    hipLaunchKernelGGL(k_prep2, dim3(576), dim3(256), 0, stream,
                       log_dt, Lambda, W, D, out_w,
                       TmB, AreB, AimB, PreB, PimB, lam64B, Wb);
    hipLaunchKernelGGL(k_scan3, dim3(2048), dim3(256), 0, stream,
                       u, TmB, AreB, AimB, PreB, PimB, lam64B, G);
    hipLaunchKernelGGL(k_tr, dim3(32, 8, 16), dim3(256), 0, stream, G, Gt);
    hipLaunchKernelGGL(k_proj, dim3(4, 16, 16), dim3(256), 0, stream,
                       Gt, Wb, out_b, out);
}